// Round 10
// baseline (201.710 us; speedup 1.0000x reference)
//
#include <hip/hip_runtime.h>
#include <hip/hip_bf16.h>
#include <stdint.h>

typedef short    bf16x8 __attribute__((ext_vector_type(8)));
typedef float    f32x4  __attribute__((ext_vector_type(4)));
typedef float    f32x16 __attribute__((ext_vector_type(16)));
typedef uint32_t u32x2  __attribute__((ext_vector_type(2)));
typedef uint32_t u32x4  __attribute__((ext_vector_type(4)));
typedef uint16_t u16x4  __attribute__((ext_vector_type(4)));

#define DEV __device__ __forceinline__
#define AS1 __attribute__((address_space(1)))
#define AS3 __attribute__((address_space(3)))

#define SM_SCALE 0.18033688011112042f   // log2(e)/sqrt(Dh) = log2(e)/8, folded into Wq

DEV uint32_t pk_bf16(float lo, float hi) {
    uint32_t r;
    asm("v_cvt_pk_bf16_f32 %0, %1, %2" : "=v"(r) : "v"(lo), "v"(hi));
    return r;
}

// async global->LDS, 16B per lane; LDS dest = wave-uniform base + lane*16
DEV void gload_lds16(const uint16_t* g, uint16_t* l) {
    __builtin_amdgcn_global_load_lds((AS1 const uint32_t*)g, (AS3 uint32_t*)l, 16, 0, 0);
}

// v_permlane32_swap_b32 a, b: a.hi(rows 2-3) <-> b.lo(rows 0-1).
// Direction HW-verified: round-4 (swapped operands) failed, round-6 (this order) passed.
DEV void plane32_swap(uint32_t& a, uint32_t& b) {
    asm("v_permlane32_swap_b32 %0, %1" : "+v"(a), "+v"(b));
}

// ---------------------------------------------------------------------------
// cast fp32 -> bf16: y in [0,3] -> weights (1M elems), y in [4,6] -> activations (4M)
// Wq (y==0) is pre-scaled by SM_SCALE so attention scores land in log2 domain.
// ---------------------------------------------------------------------------
__global__ __launch_bounds__(256) void cast_all(
    const float* __restrict__ w0, const float* __restrict__ w1,
    const float* __restrict__ w2, const float* __restrict__ w3,
    const float* __restrict__ aq, const float* __restrict__ ak, const float* __restrict__ av,
    uint16_t* __restrict__ ws)
{
    const int y = blockIdx.y;
    const float* s;
    uint16_t* d;
    if (y < 4) {
        if (blockIdx.x >= 512) return;
        s = (y == 0) ? w0 : (y == 1) ? w1 : (y == 2) ? w2 : w3;
        d = ws + ((size_t)y << 20);
    } else {
        s = (y == 4) ? aq : (y == 5) ? ak : av;
        d = ws + (size_t)(1 << 22) + ((size_t)(y - 4) << 22);
    }
    const float m = (y == 0) ? SM_SCALE : 1.0f;
    const size_t i = ((size_t)blockIdx.x * 256 + threadIdx.x) * 8;
    float4 a = *reinterpret_cast<const float4*>(s + i);
    float4 b = *reinterpret_cast<const float4*>(s + i + 4);
    u32x4 w;
    w[0] = pk_bf16(a.x * m, a.y * m); w[1] = pk_bf16(a.z * m, a.w * m);
    w[2] = pk_bf16(b.x * m, b.y * m); w[3] = pk_bf16(b.z * m, b.w * m);
    *reinterpret_cast<u32x4*>(d + i) = w;
}

// ---------------------------------------------------------------------------
// QKV GEMM (round-9 verified): BK=64 plane-split LDS, global_load_lds staging.
// blockIdx.z: 0->Q (bias scaled), 1->K, 2->V (stored transposed per head)
// ---------------------------------------------------------------------------
__global__ __launch_bounds__(256) void gemm_qkv(
    const uint16_t* __restrict__ Qc, const uint16_t* __restrict__ Kc, const uint16_t* __restrict__ Vc,
    const uint16_t* __restrict__ wqc, const uint16_t* __restrict__ wkc, const uint16_t* __restrict__ wvc,
    const float* __restrict__ bq, const float* __restrict__ bk, const float* __restrict__ bv,
    uint16_t* __restrict__ Qb, uint16_t* __restrict__ Kb, uint16_t* __restrict__ Vt)
{
    constexpr int Kd = 1024, N = 1024;
    __shared__ uint16_t Al[2][128 * 32];
    __shared__ uint16_t Bl[2][128 * 32];

    const int z = blockIdx.z;
    const uint16_t* A = (z == 0) ? Qc : (z == 1) ? Kc : Vc;
    const uint16_t* W = (z == 0) ? wqc : (z == 1) ? wkc : wvc;
    const float* bias = (z == 0) ? bq : (z == 1) ? bk : bv;
    const float bs = (z == 0) ? SM_SCALE : 1.0f;

    const int brow = blockIdx.x * 128;
    const int bcol = blockIdx.y * 128;
    const int t = threadIdx.x, lane = t & 63, wid = t >> 6;
    const int wr = wid >> 1, wc = wid & 1;

    const int srow = wid * 16 + (lane >> 2);
    const int scol = (lane & 3) * 8;
    const uint16_t* aA = A + (size_t)(brow + srow) * Kd + scol;
    const uint16_t* aW = W + (size_t)(bcol + srow) * Kd + scol;
    uint16_t* lA = &Al[0][srow * 32 + scol];
    uint16_t* lB = &Bl[0][srow * 32 + scol];

    f32x4 acc[4][4];
#pragma unroll
    for (int i = 0; i < 4; ++i)
#pragma unroll
        for (int j = 0; j < 4; ++j)
#pragma unroll
            for (int e = 0; e < 4; ++e) acc[i][j][e] = 0.f;

    const int frow = lane & 15;
    const int koff = (lane >> 4) * 8;

    for (int k0 = 0; k0 < Kd; k0 += 64) {
#pragma unroll
        for (int p = 0; p < 2; ++p) {
            gload_lds16(aA + k0 + p * 32, lA + p * 4096);
            gload_lds16(aA + k0 + p * 32 + (size_t)64 * Kd, lA + p * 4096 + 2048);
            gload_lds16(aW + k0 + p * 32, lB + p * 4096);
            gload_lds16(aW + k0 + p * 32 + (size_t)64 * Kd, lB + p * 4096 + 2048);
        }
        __syncthreads();

#pragma unroll
        for (int p = 0; p < 2; ++p) {
            bf16x8 af[4], bfr[4];
#pragma unroll
            for (int fr = 0; fr < 4; ++fr)
                af[fr] = *reinterpret_cast<const bf16x8*>(&Al[p][(wr * 64 + fr * 16 + frow) * 32 + koff]);
#pragma unroll
            for (int fc = 0; fc < 4; ++fc)
                bfr[fc] = *reinterpret_cast<const bf16x8*>(&Bl[p][(wc * 64 + fc * 16 + frow) * 32 + koff]);
#pragma unroll
            for (int fr = 0; fr < 4; ++fr)
#pragma unroll
                for (int fc = 0; fc < 4; ++fc)
                    acc[fr][fc] = __builtin_amdgcn_mfma_f32_16x16x32_bf16(af[fr], bfr[fc], acc[fr][fc], 0, 0, 0);
        }
        __syncthreads();
    }

    const int m0 = brow + wr * 64;
    const int n0 = bcol + wc * 64;
    if (z < 2) {
        uint16_t* Cb = (z == 0) ? Qb : Kb;
#pragma unroll
        for (int fc = 0; fc < 4; ++fc) {
            const int col = n0 + fc * 16 + frow;
            const float bia = bias[col] * bs;
#pragma unroll
            for (int fr = 0; fr < 4; ++fr) {
                const int mrow = m0 + fr * 16 + (lane >> 4) * 4;
                f32x4 a = acc[fr][fc];
                uint32_t w01 = pk_bf16(a[0] + bia, a[1] + bia);
                uint32_t w23 = pk_bf16(a[2] + bia, a[3] + bia);
                Cb[(size_t)(mrow + 0) * N + col] = (uint16_t)(w01 & 0xffff);
                Cb[(size_t)(mrow + 1) * N + col] = (uint16_t)(w01 >> 16);
                Cb[(size_t)(mrow + 2) * N + col] = (uint16_t)(w23 & 0xffff);
                Cb[(size_t)(mrow + 3) * N + col] = (uint16_t)(w23 >> 16);
            }
        }
    } else {
        // V: store transposed per head -> Vt[((b*16+h)*64+d)*2048 + s]
#pragma unroll
        for (int fc = 0; fc < 4; ++fc) {
            const int col = n0 + fc * 16 + frow;
            const int hh = col >> 6, dd = col & 63;
            const float bia = bias[col];
#pragma unroll
            for (int fr = 0; fr < 4; ++fr) {
                const int mrow = m0 + fr * 16 + (lane >> 4) * 4;
                const int bb = mrow >> 11, ss = mrow & 2047;
                f32x4 a = acc[fr][fc];
                uint32_t w01 = pk_bf16(a[0] + bia, a[1] + bia);
                uint32_t w23 = pk_bf16(a[2] + bia, a[3] + bia);
                u16x4 pv;
                pv[0] = (uint16_t)(w01 & 0xffff); pv[1] = (uint16_t)(w01 >> 16);
                pv[2] = (uint16_t)(w23 & 0xffff); pv[3] = (uint16_t)(w23 >> 16);
                *reinterpret_cast<u16x4*>(&Vt[(size_t)((bb * 16 + hh) * 64 + dd) * 2048 + ss]) = pv;
            }
        }
    }
}

// ---------------------------------------------------------------------------
// Flash attention, round-10: NO LDS staging, NO loop barriers. K/V fragments
// read directly from global (L2-resident: 512 KB per bh; XCD-swizzled grid
// keeps 4 bh = 2 MB per XCD L2). Per-lane K/V addresses are loop-invariant
// except a uniform +64-key advance. Math identical to round-8/9 verified
// version (KV-split across wave pairs, log2-domain online softmax, defer-max,
// permlane32_swap). LDS used only for the final cross-half combine.
// ---------------------------------------------------------------------------
__global__ __launch_bounds__(256, 4) void attn_kernel(
    const uint16_t* __restrict__ Qb, const uint16_t* __restrict__ Kb,
    const uint16_t* __restrict__ Vt, uint16_t* __restrict__ At)
{
    constexpr int S = 2048, E = 1024;
    __shared__ float ob[128 * 36];    // 18432 B: half-1 O partials
    __shared__ float mlb[128 * 2];    // m, l partials

    // bijective XCD swizzle (1024 % 8 == 0): XCD k serves bh in [4k, 4k+4)
    const int bid = blockIdx.x;
    const int swz = (bid & 7) * 128 + (bid >> 3);
    const int bh = swz >> 5;
    const int b = bh >> 4, h = bh & 15;
    const int t = threadIdx.x;
    const int lane = t & 63, wid = t >> 6;
    const int lo = lane & 31, hi = lane >> 5;
    const int half = wid >> 1;                       // KV half this wave owns
    const int q0 = (swz & 31) * 64 + (wid & 1) * 32;

    bf16x8 qf[4];
    {
        const uint16_t* qrow = Qb + (size_t)(b * S + q0 + lo) * E + h * 64;
#pragma unroll
        for (int kk = 0; kk < 4; ++kk)
            qf[kk] = *reinterpret_cast<const bf16x8*>(qrow + kk * 16 + hi * 8);
    }

    f32x16 oacc[2];
#pragma unroll
    for (int i = 0; i < 16; ++i) { oacc[0][i] = 0.f; oacc[1][i] = 0.f; }
    float mrun = -1e30f, lsum = 0.f;

    // loop-invariant per-lane bases
    const uint16_t* k0p = Kb + (size_t)(b * S + half * 1024 + lo) * E + h * 64 + hi * 8;
    const uint16_t* k1p = k0p + (size_t)32 * E;
    const uint16_t* v0p = Vt + (size_t)(bh * 64 + lo) * S + half * 1024 + hi * 8;
    const uint16_t* v1p = v0p + (size_t)32 * S;

#pragma unroll 1
    for (int i = 0; i < 16; ++i) {
        const size_t ko = (size_t)i * 64 * E;        // advance 64 key rows
        const int    vo = i * 64;                    // advance 64 key cols

        // ---- S^T = K @ Q^T (scores already in log2 domain) ----
        f32x16 sacc[2];
#pragma unroll
        for (int j = 0; j < 16; ++j) { sacc[0][j] = 0.f; sacc[1][j] = 0.f; }
        __builtin_amdgcn_s_setprio(1);
#pragma unroll
        for (int kk = 0; kk < 4; ++kk) {
            bf16x8 ka0 = *reinterpret_cast<const bf16x8*>(k0p + ko + kk * 16);
            bf16x8 ka1 = *reinterpret_cast<const bf16x8*>(k1p + ko + kk * 16);
            sacc[0] = __builtin_amdgcn_mfma_f32_32x32x16_bf16(ka0, qf[kk], sacc[0], 0, 0, 0);
            sacc[1] = __builtin_amdgcn_mfma_f32_32x32x16_bf16(ka1, qf[kk], sacc[1], 0, 0, 0);
        }
        __builtin_amdgcn_s_setprio(0);

        // ---- tree max over 32 values + partner half-lane ----
        float tm[16];
#pragma unroll
        for (int j = 0; j < 16; ++j) tm[j] = fmaxf(sacc[0][j], sacc[1][j]);
#pragma unroll
        for (int s = 8; s > 0; s >>= 1)
#pragma unroll
            for (int j = 0; j < 8; ++j)
                if (j < s) tm[j] = fmaxf(tm[j], tm[j + s]);
        float pmax = tm[0];
        pmax = fmaxf(pmax, __shfl_xor(pmax, 32, 64));

        // ---- defer-max: rescale only when max grew by > 3 (P <= 2^3 = 8) ----
        if (!__all(pmax - mrun <= 3.0f)) {
            float mnew = fmaxf(mrun, pmax);
            float corr = __builtin_amdgcn_exp2f(mrun - mnew);
            lsum *= corr;
#pragma unroll
            for (int j = 0; j < 16; ++j) { oacc[0][j] *= corr; oacc[1][j] *= corr; }
            mrun = mnew;
        }

        // ---- P = exp2(S - m), packed to bf16 pairs; 4-way partial sums ----
        uint32_t w[16];
        float ps0 = 0.f, ps1 = 0.f, ps2 = 0.f, ps3 = 0.f;
#pragma unroll
        for (int kf = 0; kf < 2; ++kf)
#pragma unroll
            for (int j = 0; j < 8; ++j) {
                float pa = __builtin_amdgcn_exp2f(sacc[kf][2 * j]     - mrun);
                float pb = __builtin_amdgcn_exp2f(sacc[kf][2 * j + 1] - mrun);
                if (j & 1) { ps0 += pa; ps1 += pb; } else { ps2 += pa; ps3 += pb; }
                w[kf * 8 + j] = pk_bf16(pa, pb);
            }
        lsum += (ps0 + ps1) + (ps2 + ps3);   // cross-half-lane exchange deferred

        // ---- PV: O^T[d,q] += Vt[d,key] * P^T[key,q] ----
        __builtin_amdgcn_s_setprio(1);
#pragma unroll
        for (int ks = 0; ks < 4; ++ks) {
            const int base = (ks >> 1) * 8 + (ks & 1) * 4;
            uint32_t p0 = w[base + 0], p2 = w[base + 2];
            uint32_t p1 = w[base + 1], p3 = w[base + 3];
            plane32_swap(p0, p2);
            plane32_swap(p1, p3);
            u32x4 pw; pw[0] = p0; pw[1] = p1; pw[2] = p2; pw[3] = p3;
            bf16x8 pf = __builtin_bit_cast(bf16x8, pw);
            bf16x8 vf0 = *reinterpret_cast<const bf16x8*>(v0p + vo + ks * 16);
            bf16x8 vf1 = *reinterpret_cast<const bf16x8*>(v1p + vo + ks * 16);
            oacc[0] = __builtin_amdgcn_mfma_f32_32x32x16_bf16(vf0, pf, oacc[0], 0, 0, 0);
            oacc[1] = __builtin_amdgcn_mfma_f32_32x32x16_bf16(vf1, pf, oacc[1], 0, 0, 0);
        }
        __builtin_amdgcn_s_setprio(0);
    }

    // full-row l (lane^32 partner holds the other 16 keys of each tile)
    lsum += __shfl_xor(lsum, 32, 64);

    // ---- in-block combine: half-1 publishes (m,l,O); half-0 merges ----
    const int w2 = wid & 1;
    if (half == 1) {
        float* dst = ob + (w2 * 64 + lane) * 36;
#pragma unroll
        for (int df = 0; df < 2; ++df)
#pragma unroll
            for (int j = 0; j < 16; ++j) dst[df * 16 + j] = oacc[df][j];
        mlb[(w2 * 64 + lane) * 2]     = mrun;
        mlb[(w2 * 64 + lane) * 2 + 1] = lsum;
    }
    __syncthreads();
    if (half == 0) {
        const float* src = ob + (w2 * 64 + lane) * 36;
        const float m1 = mlb[(w2 * 64 + lane) * 2];
        const float l1 = mlb[(w2 * 64 + lane) * 2 + 1];
        const float m  = fmaxf(mrun, m1);
        const float c0 = __builtin_amdgcn_exp2f(mrun - m);
        const float c1 = __builtin_amdgcn_exp2f(m1 - m);
        const float inv = 1.0f / (c0 * lsum + c1 * l1);
        uint16_t* orow = At + (size_t)(b * S + q0 + lo) * E + h * 64;
#pragma unroll
        for (int df = 0; df < 2; ++df)
#pragma unroll
            for (int g = 0; g < 4; ++g) {
                float e0 = (c0 * oacc[df][4 * g + 0] + c1 * src[df * 16 + 4 * g + 0]) * inv;
                float e1 = (c0 * oacc[df][4 * g + 1] + c1 * src[df * 16 + 4 * g + 1]) * inv;
                float e2 = (c0 * oacc[df][4 * g + 2] + c1 * src[df * 16 + 4 * g + 2]) * inv;
                float e3 = (c0 * oacc[df][4 * g + 3] + c1 * src[df * 16 + 4 * g + 3]) * inv;
                uint32_t w01 = pk_bf16(e0, e1);
                uint32_t w23 = pk_bf16(e2, e3);
                u32x2 o2; o2[0] = w01; o2[1] = w23;
                *reinterpret_cast<u32x2*>(orow + df * 32 + 8 * g + 4 * hi) = o2;
            }
    }
}

// ---------------------------------------------------------------------------
// Output projection (round-9 verified): BK=64 plane-split structure.
// ---------------------------------------------------------------------------
__global__ __launch_bounds__(256) void gemm_out(
    const uint16_t* __restrict__ Atn, const uint16_t* __restrict__ woc,
    const float* __restrict__ bo, float* __restrict__ out)
{
    constexpr int Kd = 1024, N = 1024;
    __shared__ uint16_t Al[2][128 * 32];
    __shared__ uint16_t Bl[2][128 * 32];

    const int brow = blockIdx.x * 128;
    const int bcol = blockIdx.y * 128;
    const int t = threadIdx.x, lane = t & 63, wid = t >> 6;
    const int wr = wid >> 1, wc = wid & 1;

    const int srow = wid * 16 + (lane >> 2);
    const int scol = (lane & 3) * 8;
    const uint16_t* aA = Atn + (size_t)(brow + srow) * Kd + scol;
    const uint16_t* aW = woc + (size_t)(bcol + srow) * Kd + scol;
    uint16_t* lA = &Al[0][srow * 32 + scol];
    uint16_t* lB = &Bl[0][srow * 32 + scol];

    f32x4 acc[4][4];
#pragma unroll
    for (int i = 0; i < 4; ++i)
#pragma unroll
        for (int j = 0; j < 4; ++j)
#pragma unroll
            for (int e = 0; e < 4; ++e) acc[i][j][e] = 0.f;

    const int frow = lane & 15;
    const int koff = (lane >> 4) * 8;

    for (int k0 = 0; k0 < Kd; k0 += 64) {
#pragma unroll
        for (int p = 0; p < 2; ++p) {
            gload_lds16(aA + k0 + p * 32, lA + p * 4096);
            gload_lds16(aA + k0 + p * 32 + (size_t)64 * Kd, lA + p * 4096 + 2048);
            gload_lds16(aW + k0 + p * 32, lB + p * 4096);
            gload_lds16(aW + k0 + p * 32 + (size_t)64 * Kd, lB + p * 4096 + 2048);
        }
        __syncthreads();

#pragma unroll
        for (int p = 0; p < 2; ++p) {
            bf16x8 af[4], bfr[4];
#pragma unroll
            for (int fr = 0; fr < 4; ++fr)
                af[fr] = *reinterpret_cast<const bf16x8*>(&Al[p][(wr * 64 + fr * 16 + frow) * 32 + koff]);
#pragma unroll
            for (int fc = 0; fc < 4; ++fc)
                bfr[fc] = *reinterpret_cast<const bf16x8*>(&Bl[p][(wc * 64 + fc * 16 + frow) * 32 + koff]);
#pragma unroll
            for (int fr = 0; fr < 4; ++fr)
#pragma unroll
                for (int fc = 0; fc < 4; ++fc)
                    acc[fr][fc] = __builtin_amdgcn_mfma_f32_16x16x32_bf16(af[fr], bfr[fc], acc[fr][fc], 0, 0, 0);
        }
        __syncthreads();
    }

    const int m0 = brow + wr * 64;
    const int n0 = bcol + wc * 64;
#pragma unroll
    for (int fc = 0; fc < 4; ++fc) {
        const int col = n0 + fc * 16 + frow;
        const float bia = bo[col];
#pragma unroll
        for (int fr = 0; fr < 4; ++fr) {
            const int mrow = m0 + fr * 16 + (lane >> 4) * 4;
#pragma unroll
            for (int j = 0; j < 4; ++j)
                out[(size_t)(mrow + j) * N + col] = acc[fr][fc][j] + bia;
        }
    }
}

// ---------------------------------------------------------------------------
extern "C" void kernel_launch(void* const* d_in, const int* in_sizes, int n_in,
                              void* d_out, int out_size, void* d_ws, size_t ws_size,
                              hipStream_t stream)
{
    const float* key   = (const float*)d_in[0];
    const float* query = (const float*)d_in[1];
    const float* value = (const float*)d_in[2];
    const float* Wq = (const float*)d_in[3];
    const float* bq = (const float*)d_in[4];
    const float* Wk = (const float*)d_in[5];
    const float* bk = (const float*)d_in[6];
    const float* Wv = (const float*)d_in[7];
    const float* bv = (const float*)d_in[8];
    const float* Wo = (const float*)d_in[9];
    const float* bo = (const float*)d_in[10];

    uint16_t* ws = (uint16_t*)d_ws;
    uint16_t* wqc = ws;                                 // 4 x 1M weights
    uint16_t* wkc = ws + ((size_t)1 << 20);
    uint16_t* wvc = ws + ((size_t)2 << 20);
    uint16_t* woc = ws + ((size_t)3 << 20);
    uint16_t* Qc  = ws + ((size_t)1 << 22);             // 3 x 4M bf16 activations
    uint16_t* Kc  = ws + ((size_t)2 << 22);
    uint16_t* Vc  = ws + ((size_t)3 << 22);
    uint16_t* Qb  = ws + ((size_t)4 << 22);             // projected Q/K, V^T
    uint16_t* Kb  = ws + ((size_t)5 << 22);
    uint16_t* Vt  = ws + ((size_t)6 << 22);
    uint16_t* At  = Qc;                                 // alias: Qc dead after gemm_qkv
    float* out = (float*)d_out;

    cast_all<<<dim3(2048, 7), 256, 0, stream>>>(Wq, Wk, Wv, Wo, query, key, value, ws);
    gemm_qkv<<<dim3(32, 8, 3), 256, 0, stream>>>(Qc, Kc, Vc, wqc, wkc, wvc,
                                                 bq, bk, bv, Qb, Kb, Vt);
    attn_kernel<<<dim3(1024), 256, 0, stream>>>(Qb, Kb, Vt, At);
    gemm_out<<<dim3(32, 8), 256, 0, stream>>>(At, woc, bo, out);
}

// Round 11
// 141.663 us; speedup vs baseline: 1.4239x; 1.4239x over previous
//
#include <hip/hip_runtime.h>
#include <hip/hip_bf16.h>
#include <stdint.h>

typedef short    bf16x8 __attribute__((ext_vector_type(8)));
typedef float    f32x4  __attribute__((ext_vector_type(4)));
typedef float    f32x16 __attribute__((ext_vector_type(16)));
typedef uint32_t u32x2  __attribute__((ext_vector_type(2)));
typedef uint32_t u32x4  __attribute__((ext_vector_type(4)));
typedef uint16_t u16x4  __attribute__((ext_vector_type(4)));

#define DEV __device__ __forceinline__
#define AS1 __attribute__((address_space(1)))
#define AS3 __attribute__((address_space(3)))

#define SM_SCALE 0.18033688011112042f   // log2(e)/sqrt(Dh) = log2(e)/8, folded into Wq

DEV uint32_t pk_bf16(float lo, float hi) {
    uint32_t r;
    asm("v_cvt_pk_bf16_f32 %0, %1, %2" : "=v"(r) : "v"(lo), "v"(hi));
    return r;
}

// async global->LDS, 16B per lane; LDS dest = wave-uniform base + lane*16
DEV void gload_lds16(const void* g, void* l) {
    __builtin_amdgcn_global_load_lds((AS1 const uint32_t*)g, (AS3 uint32_t*)l, 16, 0, 0);
}

// v_permlane32_swap_b32 a, b: a.hi(rows 2-3) <-> b.lo(rows 0-1).
// Direction HW-verified: round-4 (swapped operands) failed, round-6 (this order) passed.
DEV void plane32_swap(uint32_t& a, uint32_t& b) {
    asm("v_permlane32_swap_b32 %0, %1" : "+v"(a), "+v"(b));
}

// ---------------------------------------------------------------------------
// cast fp32 -> bf16, WEIGHTS ONLY (activations now cast in-gemm).
// Wq (y==0) is pre-scaled by SM_SCALE so attention scores land in log2 domain.
// ---------------------------------------------------------------------------
__global__ __launch_bounds__(256) void cast_w(
    const float* __restrict__ w0, const float* __restrict__ w1,
    const float* __restrict__ w2, const float* __restrict__ w3,
    uint16_t* __restrict__ ws)
{
    const int y = blockIdx.y;
    const float* s = (y == 0) ? w0 : (y == 1) ? w1 : (y == 2) ? w2 : w3;
    uint16_t* d = ws + ((size_t)y << 20);
    const float m = (y == 0) ? SM_SCALE : 1.0f;
    const size_t i = ((size_t)blockIdx.x * 256 + threadIdx.x) * 8;
    float4 a = *reinterpret_cast<const float4*>(s + i);
    float4 b = *reinterpret_cast<const float4*>(s + i + 4);
    u32x4 w;
    w[0] = pk_bf16(a.x * m, a.y * m); w[1] = pk_bf16(a.z * m, a.w * m);
    w[2] = pk_bf16(b.x * m, b.y * m); w[3] = pk_bf16(b.z * m, b.w * m);
    *reinterpret_cast<u32x4*>(d + i) = w;
}

// ---------------------------------------------------------------------------
// QKV GEMM, round-11: A read as fp32 directly from inputs (cast fused at
// fragment-load via cvt_pk, numerically identical RTNE). A staged into 4 LDS
// planes of [128][16] floats (64B rows, same bank pattern as verified bf16
// layout); B bf16 2-plane as round-9. BK=64, 128x128 tile.
// blockIdx.z: 0->Q (weights pre-scaled, bias scaled), 1->K, 2->V (stored V^T)
// ---------------------------------------------------------------------------
__global__ __launch_bounds__(256) void gemm_qkv(
    const float* __restrict__ Aq, const float* __restrict__ Ak, const float* __restrict__ Av,
    const uint16_t* __restrict__ wqc, const uint16_t* __restrict__ wkc, const uint16_t* __restrict__ wvc,
    const float* __restrict__ bq, const float* __restrict__ bk, const float* __restrict__ bv,
    uint16_t* __restrict__ Qb, uint16_t* __restrict__ Kb, uint16_t* __restrict__ Vt)
{
    constexpr int Kd = 1024, N = 1024;
    __shared__ float    Afl[4][128 * 16];   // plane q: k in [16q, 16q+16), 32 KB
    __shared__ uint16_t Bl[2][128 * 32];    // plane p: k in [32p, 32p+32), 16 KB

    const int z = blockIdx.z;
    const float*    A = (z == 0) ? Aq : (z == 1) ? Ak : Av;
    const uint16_t* W = (z == 0) ? wqc : (z == 1) ? wkc : wvc;
    const float* bias = (z == 0) ? bq : (z == 1) ? bk : bv;
    const float bs = (z == 0) ? SM_SCALE : 1.0f;

    const int brow = blockIdx.x * 128;
    const int bcol = blockIdx.y * 128;
    const int t = threadIdx.x, lane = t & 63, wid = t >> 6;
    const int wr = wid >> 1, wc = wid & 1;

    // A staging: row = rh*64 + wid*16 + (lane>>2), 4 floats at (lane&3)*4
    const int srow = wid * 16 + (lane >> 2);
    const float* aA = A + (size_t)(brow + srow) * Kd + (lane & 3) * 4;
    float* lAf = &Afl[0][0] + (size_t)wid * 256 + (size_t)(lane >> 2) * 16 + (lane & 3) * 4;
    // B staging: row = rh*64 + wid*16 + (lane>>2), 8 bf16 at (lane&3)*8
    const uint16_t* aW = W + (size_t)(bcol + srow) * Kd + (lane & 3) * 8;
    uint16_t* lB = &Bl[0][srow * 32 + (lane & 3) * 8];

    f32x4 acc[4][4];
#pragma unroll
    for (int i = 0; i < 4; ++i)
#pragma unroll
        for (int j = 0; j < 4; ++j)
#pragma unroll
            for (int e = 0; e < 4; ++e) acc[i][j][e] = 0.f;

    const int frow = lane & 15;
    const int qsel = (lane >> 5);            // which 16-k plane within 32-k window
    const int foff = ((lane >> 4) & 1) * 8;  // float offset within plane row
    const int koff = (lane >> 4) * 8;        // bf16 offset for B

    for (int k0 = 0; k0 < Kd; k0 += 64) {
        // ---- stage A (fp32, 8 gloads) and B (bf16, 4 gloads) ----
#pragma unroll
        for (int q = 0; q < 4; ++q) {
#pragma unroll
            for (int rh = 0; rh < 2; ++rh)
                gload_lds16(aA + k0 + q * 16 + (size_t)rh * 64 * Kd,
                            lAf + q * 2048 + rh * 1024);
        }
#pragma unroll
        for (int p = 0; p < 2; ++p) {
            gload_lds16(aW + k0 + p * 32, lB + p * 4096);
            gload_lds16(aW + k0 + p * 32 + (size_t)64 * Kd, lB + p * 4096 + 2048);
        }
        __syncthreads();

#pragma unroll
        for (int p = 0; p < 2; ++p) {
            bf16x8 af[4], bfr[4];
#pragma unroll
            for (int fr = 0; fr < 4; ++fr) {
                const float* ap = &Afl[2 * p + qsel][(wr * 64 + fr * 16 + frow) * 16 + foff];
                f32x4 lo4 = *reinterpret_cast<const f32x4*>(ap);
                f32x4 hi4 = *reinterpret_cast<const f32x4*>(ap + 4);
                u32x4 aw;
                aw[0] = pk_bf16(lo4[0], lo4[1]); aw[1] = pk_bf16(lo4[2], lo4[3]);
                aw[2] = pk_bf16(hi4[0], hi4[1]); aw[3] = pk_bf16(hi4[2], hi4[3]);
                af[fr] = __builtin_bit_cast(bf16x8, aw);
            }
#pragma unroll
            for (int fc = 0; fc < 4; ++fc)
                bfr[fc] = *reinterpret_cast<const bf16x8*>(&Bl[p][(wc * 64 + fc * 16 + frow) * 32 + koff]);
#pragma unroll
            for (int fr = 0; fr < 4; ++fr)
#pragma unroll
                for (int fc = 0; fc < 4; ++fc)
                    acc[fr][fc] = __builtin_amdgcn_mfma_f32_16x16x32_bf16(af[fr], bfr[fc], acc[fr][fc], 0, 0, 0);
        }
        __syncthreads();
    }

    const int m0 = brow + wr * 64;
    const int n0 = bcol + wc * 64;
    if (z < 2) {
        uint16_t* Cb = (z == 0) ? Qb : Kb;
#pragma unroll
        for (int fc = 0; fc < 4; ++fc) {
            const int col = n0 + fc * 16 + frow;
            const float bia = bias[col] * bs;
#pragma unroll
            for (int fr = 0; fr < 4; ++fr) {
                const int mrow = m0 + fr * 16 + (lane >> 4) * 4;
                f32x4 a = acc[fr][fc];
                uint32_t w01 = pk_bf16(a[0] + bia, a[1] + bia);
                uint32_t w23 = pk_bf16(a[2] + bia, a[3] + bia);
                Cb[(size_t)(mrow + 0) * N + col] = (uint16_t)(w01 & 0xffff);
                Cb[(size_t)(mrow + 1) * N + col] = (uint16_t)(w01 >> 16);
                Cb[(size_t)(mrow + 2) * N + col] = (uint16_t)(w23 & 0xffff);
                Cb[(size_t)(mrow + 3) * N + col] = (uint16_t)(w23 >> 16);
            }
        }
    } else {
        // V: store transposed per head -> Vt[((b*16+h)*64+d)*2048 + s]
#pragma unroll
        for (int fc = 0; fc < 4; ++fc) {
            const int col = n0 + fc * 16 + frow;
            const int hh = col >> 6, dd = col & 63;
            const float bia = bias[col];
#pragma unroll
            for (int fr = 0; fr < 4; ++fr) {
                const int mrow = m0 + fr * 16 + (lane >> 4) * 4;
                const int bb = mrow >> 11, ss = mrow & 2047;
                f32x4 a = acc[fr][fc];
                uint32_t w01 = pk_bf16(a[0] + bia, a[1] + bia);
                uint32_t w23 = pk_bf16(a[2] + bia, a[3] + bia);
                u16x4 pv;
                pv[0] = (uint16_t)(w01 & 0xffff); pv[1] = (uint16_t)(w01 >> 16);
                pv[2] = (uint16_t)(w23 & 0xffff); pv[3] = (uint16_t)(w23 >> 16);
                *reinterpret_cast<u16x4*>(&Vt[(size_t)((bb * 16 + hh) * 64 + dd) * 2048 + ss]) = pv;
            }
        }
    }
}

// ---------------------------------------------------------------------------
// Flash attention (round-9 verified, reverted verbatim): in-block KV-split,
// LDS-staged K/V, 2 barriers/tile, 4 blocks/CU.
// ---------------------------------------------------------------------------
__global__ __launch_bounds__(256, 4) void attn_kernel(
    const uint16_t* __restrict__ Qb, const uint16_t* __restrict__ Kb,
    const uint16_t* __restrict__ Vt, uint16_t* __restrict__ At)
{
    constexpr int S = 2048, E = 1024;
    __shared__ uint16_t Kl[2][64 * 72];
    __shared__ uint16_t Vl[2][64 * 72];

    const int bh = blockIdx.y;
    const int b = bh >> 4, h = bh & 15;
    const int t = threadIdx.x;
    const int lane = t & 63, wid = t >> 6;
    const int lo = lane & 31, hi = lane >> 5;
    const int half = wid >> 1;
    const int q0 = blockIdx.x * 64 + (wid & 1) * 32;

    bf16x8 qf[4];
    {
        const uint16_t* qrow = Qb + (size_t)(b * S + q0 + lo) * E + h * 64;
#pragma unroll
        for (int kk = 0; kk < 4; ++kk)
            qf[kk] = *reinterpret_cast<const bf16x8*>(qrow + kk * 16 + hi * 8);
    }

    f32x16 oacc[2];
#pragma unroll
    for (int i = 0; i < 16; ++i) { oacc[0][i] = 0.f; oacc[1][i] = 0.f; }
    float mrun = -1e30f, lsum = 0.f;

    const uint16_t* Kbase = Kb + (size_t)(b * S) * E + h * 64;
    const uint16_t* Vbase = Vt + (size_t)(bh * 64) * S;

    const int r = t >> 2, seg = t & 3;
    const int lds_off = r * 72 + seg * 16;

#pragma unroll 1
    for (int i = 0; i < 16; ++i) {
        {
            const uint16_t* ksa = Kbase + (size_t)(i * 64 + r) * E + seg * 16;
            const uint16_t* vsa = Vbase + (size_t)r * S + i * 64 + seg * 16;
            const uint16_t* ksb = ksa + (size_t)1024 * E;
            const uint16_t* vsb = vsa + 1024;
            u32x4 k0a = *reinterpret_cast<const u32x4*>(ksa);
            u32x4 k1a = *reinterpret_cast<const u32x4*>(ksa + 8);
            u32x4 v0a = *reinterpret_cast<const u32x4*>(vsa);
            u32x4 v1a = *reinterpret_cast<const u32x4*>(vsa + 8);
            u32x4 k0b = *reinterpret_cast<const u32x4*>(ksb);
            u32x4 k1b = *reinterpret_cast<const u32x4*>(ksb + 8);
            u32x4 v0b = *reinterpret_cast<const u32x4*>(vsb);
            u32x4 v1b = *reinterpret_cast<const u32x4*>(vsb + 8);
            *reinterpret_cast<u32x4*>(&Kl[0][lds_off])     = k0a;
            *reinterpret_cast<u32x4*>(&Kl[0][lds_off + 8]) = k1a;
            *reinterpret_cast<u32x4*>(&Vl[0][lds_off])     = v0a;
            *reinterpret_cast<u32x4*>(&Vl[0][lds_off + 8]) = v1a;
            *reinterpret_cast<u32x4*>(&Kl[1][lds_off])     = k0b;
            *reinterpret_cast<u32x4*>(&Kl[1][lds_off + 8]) = k1b;
            *reinterpret_cast<u32x4*>(&Vl[1][lds_off])     = v0b;
            *reinterpret_cast<u32x4*>(&Vl[1][lds_off + 8]) = v1b;
        }
        __syncthreads();

        f32x16 sacc[2];
#pragma unroll
        for (int j = 0; j < 16; ++j) { sacc[0][j] = 0.f; sacc[1][j] = 0.f; }
        __builtin_amdgcn_s_setprio(1);
#pragma unroll
        for (int kk = 0; kk < 4; ++kk) {
            bf16x8 ka0 = *reinterpret_cast<const bf16x8*>(&Kl[half][lo * 72 + kk * 16 + hi * 8]);
            bf16x8 ka1 = *reinterpret_cast<const bf16x8*>(&Kl[half][(32 + lo) * 72 + kk * 16 + hi * 8]);
            sacc[0] = __builtin_amdgcn_mfma_f32_32x32x16_bf16(ka0, qf[kk], sacc[0], 0, 0, 0);
            sacc[1] = __builtin_amdgcn_mfma_f32_32x32x16_bf16(ka1, qf[kk], sacc[1], 0, 0, 0);
        }
        __builtin_amdgcn_s_setprio(0);

        float tm[16];
#pragma unroll
        for (int j = 0; j < 16; ++j) tm[j] = fmaxf(sacc[0][j], sacc[1][j]);
#pragma unroll
        for (int s = 8; s > 0; s >>= 1)
#pragma unroll
            for (int j = 0; j < 8; ++j)
                if (j < s) tm[j] = fmaxf(tm[j], tm[j + s]);
        float pmax = tm[0];
        pmax = fmaxf(pmax, __shfl_xor(pmax, 32, 64));

        if (!__all(pmax - mrun <= 3.0f)) {
            float mnew = fmaxf(mrun, pmax);
            float corr = __builtin_amdgcn_exp2f(mrun - mnew);
            lsum *= corr;
#pragma unroll
            for (int j = 0; j < 16; ++j) { oacc[0][j] *= corr; oacc[1][j] *= corr; }
            mrun = mnew;
        }

        uint32_t w[16];
        float ps0 = 0.f, ps1 = 0.f, ps2 = 0.f, ps3 = 0.f;
#pragma unroll
        for (int kf = 0; kf < 2; ++kf)
#pragma unroll
            for (int j = 0; j < 8; ++j) {
                float pa = __builtin_amdgcn_exp2f(sacc[kf][2 * j]     - mrun);
                float pb = __builtin_amdgcn_exp2f(sacc[kf][2 * j + 1] - mrun);
                if (j & 1) { ps0 += pa; ps1 += pb; } else { ps2 += pa; ps3 += pb; }
                w[kf * 8 + j] = pk_bf16(pa, pb);
            }
        lsum += (ps0 + ps1) + (ps2 + ps3);

        __builtin_amdgcn_s_setprio(1);
#pragma unroll
        for (int ks = 0; ks < 4; ++ks) {
            const int base = (ks >> 1) * 8 + (ks & 1) * 4;
            uint32_t p0 = w[base + 0], p2 = w[base + 2];
            uint32_t p1 = w[base + 1], p3 = w[base + 3];
            plane32_swap(p0, p2);
            plane32_swap(p1, p3);
            u32x4 pw; pw[0] = p0; pw[1] = p1; pw[2] = p2; pw[3] = p3;
            bf16x8 pf = __builtin_bit_cast(bf16x8, pw);
#pragma unroll
            for (int df = 0; df < 2; ++df) {
                bf16x8 vf = *reinterpret_cast<const bf16x8*>(&Vl[half][(df * 32 + lo) * 72 + ks * 16 + hi * 8]);
                oacc[df] = __builtin_amdgcn_mfma_f32_32x32x16_bf16(vf, pf, oacc[df], 0, 0, 0);
            }
        }
        __builtin_amdgcn_s_setprio(0);
        __syncthreads();
    }

    lsum += __shfl_xor(lsum, 32, 64);

    float* ob  = reinterpret_cast<float*>(&Kl[0][0]);
    float* mlb = reinterpret_cast<float*>(&Vl[0][0]);
    const int w2 = wid & 1;
    if (half == 1) {
        float* dst = ob + (w2 * 64 + lane) * 36;
#pragma unroll
        for (int df = 0; df < 2; ++df)
#pragma unroll
            for (int j = 0; j < 16; ++j) dst[df * 16 + j] = oacc[df][j];
        mlb[(w2 * 64 + lane) * 2]     = mrun;
        mlb[(w2 * 64 + lane) * 2 + 1] = lsum;
    }
    __syncthreads();
    if (half == 0) {
        const float* src = ob + (w2 * 64 + lane) * 36;
        const float m1 = mlb[(w2 * 64 + lane) * 2];
        const float l1 = mlb[(w2 * 64 + lane) * 2 + 1];
        const float m  = fmaxf(mrun, m1);
        const float c0 = __builtin_amdgcn_exp2f(mrun - m);
        const float c1 = __builtin_amdgcn_exp2f(m1 - m);
        const float inv = 1.0f / (c0 * lsum + c1 * l1);
        uint16_t* orow = At + (size_t)(b * S + q0 + lo) * E + h * 64;
#pragma unroll
        for (int df = 0; df < 2; ++df)
#pragma unroll
            for (int g = 0; g < 4; ++g) {
                float e0 = (c0 * oacc[df][4 * g + 0] + c1 * src[df * 16 + 4 * g + 0]) * inv;
                float e1 = (c0 * oacc[df][4 * g + 1] + c1 * src[df * 16 + 4 * g + 1]) * inv;
                float e2 = (c0 * oacc[df][4 * g + 2] + c1 * src[df * 16 + 4 * g + 2]) * inv;
                float e3 = (c0 * oacc[df][4 * g + 3] + c1 * src[df * 16 + 4 * g + 3]) * inv;
                uint32_t w01 = pk_bf16(e0, e1);
                uint32_t w23 = pk_bf16(e2, e3);
                u32x2 o2; o2[0] = w01; o2[1] = w23;
                *reinterpret_cast<u32x2*>(orow + df * 32 + 8 * g + 4 * hi) = o2;
            }
    }
}

// ---------------------------------------------------------------------------
// Output projection (round-9 verified): BK=64 plane-split structure.
// ---------------------------------------------------------------------------
__global__ __launch_bounds__(256) void gemm_out(
    const uint16_t* __restrict__ Atn, const uint16_t* __restrict__ woc,
    const float* __restrict__ bo, float* __restrict__ out)
{
    constexpr int Kd = 1024, N = 1024;
    __shared__ uint16_t Al[2][128 * 32];
    __shared__ uint16_t Bl[2][128 * 32];

    const int brow = blockIdx.x * 128;
    const int bcol = blockIdx.y * 128;
    const int t = threadIdx.x, lane = t & 63, wid = t >> 6;
    const int wr = wid >> 1, wc = wid & 1;

    const int srow = wid * 16 + (lane >> 2);
    const int scol = (lane & 3) * 8;
    const uint16_t* aA = Atn + (size_t)(brow + srow) * Kd + scol;
    const uint16_t* aW = woc + (size_t)(bcol + srow) * Kd + scol;
    uint16_t* lA = &Al[0][srow * 32 + scol];
    uint16_t* lB = &Bl[0][srow * 32 + scol];

    f32x4 acc[4][4];
#pragma unroll
    for (int i = 0; i < 4; ++i)
#pragma unroll
        for (int j = 0; j < 4; ++j)
#pragma unroll
            for (int e = 0; e < 4; ++e) acc[i][j][e] = 0.f;

    const int frow = lane & 15;
    const int koff = (lane >> 4) * 8;

    for (int k0 = 0; k0 < Kd; k0 += 64) {
#pragma unroll
        for (int p = 0; p < 2; ++p) {
            gload_lds16(aA + k0 + p * 32, lA + p * 4096);
            gload_lds16(aA + k0 + p * 32 + (size_t)64 * Kd, lA + p * 4096 + 2048);
            gload_lds16(aW + k0 + p * 32, lB + p * 4096);
            gload_lds16(aW + k0 + p * 32 + (size_t)64 * Kd, lB + p * 4096 + 2048);
        }
        __syncthreads();

#pragma unroll
        for (int p = 0; p < 2; ++p) {
            bf16x8 af[4], bfr[4];
#pragma unroll
            for (int fr = 0; fr < 4; ++fr)
                af[fr] = *reinterpret_cast<const bf16x8*>(&Al[p][(wr * 64 + fr * 16 + frow) * 32 + koff]);
#pragma unroll
            for (int fc = 0; fc < 4; ++fc)
                bfr[fc] = *reinterpret_cast<const bf16x8*>(&Bl[p][(wc * 64 + fc * 16 + frow) * 32 + koff]);
#pragma unroll
            for (int fr = 0; fr < 4; ++fr)
#pragma unroll
                for (int fc = 0; fc < 4; ++fc)
                    acc[fr][fc] = __builtin_amdgcn_mfma_f32_16x16x32_bf16(af[fr], bfr[fc], acc[fr][fc], 0, 0, 0);
        }
        __syncthreads();
    }

    const int m0 = brow + wr * 64;
    const int n0 = bcol + wc * 64;
#pragma unroll
    for (int fc = 0; fc < 4; ++fc) {
        const int col = n0 + fc * 16 + frow;
        const float bia = bo[col];
#pragma unroll
        for (int fr = 0; fr < 4; ++fr) {
            const int mrow = m0 + fr * 16 + (lane >> 4) * 4;
#pragma unroll
            for (int j = 0; j < 4; ++j)
                out[(size_t)(mrow + j) * N + col] = acc[fr][fc][j] + bia;
        }
    }
}

// ---------------------------------------------------------------------------
extern "C" void kernel_launch(void* const* d_in, const int* in_sizes, int n_in,
                              void* d_out, int out_size, void* d_ws, size_t ws_size,
                              hipStream_t stream)
{
    const float* key   = (const float*)d_in[0];
    const float* query = (const float*)d_in[1];
    const float* value = (const float*)d_in[2];
    const float* Wq = (const float*)d_in[3];
    const float* bq = (const float*)d_in[4];
    const float* Wk = (const float*)d_in[5];
    const float* bk = (const float*)d_in[6];
    const float* Wv = (const float*)d_in[7];
    const float* bv = (const float*)d_in[8];
    const float* Wo = (const float*)d_in[9];
    const float* bo = (const float*)d_in[10];

    uint16_t* ws = (uint16_t*)d_ws;
    uint16_t* wqc = ws;                                 // 4 x 1M weights
    uint16_t* wkc = ws + ((size_t)1 << 20);
    uint16_t* wvc = ws + ((size_t)2 << 20);
    uint16_t* woc = ws + ((size_t)3 << 20);
    uint16_t* Qb  = ws + ((size_t)1 << 22);             // projected Q/K, V^T, attn out
    uint16_t* Kb  = ws + ((size_t)2 << 22);
    uint16_t* Vt  = ws + ((size_t)3 << 22);
    uint16_t* At  = ws + ((size_t)4 << 22);
    float* out = (float*)d_out;

    cast_w<<<dim3(512, 4), 256, 0, stream>>>(Wq, Wk, Wv, Wo, ws);
    gemm_qkv<<<dim3(32, 8, 3), 256, 0, stream>>>(query, key, value, wqc, wkc, wvc,
                                                 bq, bk, bv, Qb, Kb, Vt);
    attn_kernel<<<dim3(32, 32), 256, 0, stream>>>(Qb, Kb, Vt, At);
    gemm_out<<<dim3(32, 8), 256, 0, stream>>>(At, woc, bo, out);
}

// Round 12
// 130.015 us; speedup vs baseline: 1.5514x; 1.0896x over previous
//
#include <hip/hip_runtime.h>
#include <hip/hip_bf16.h>
#include <stdint.h>

typedef short    bf16x8 __attribute__((ext_vector_type(8)));
typedef float    f32x4  __attribute__((ext_vector_type(4)));
typedef float    f32x16 __attribute__((ext_vector_type(16)));
typedef uint32_t u32x2  __attribute__((ext_vector_type(2)));
typedef uint32_t u32x4  __attribute__((ext_vector_type(4)));
typedef uint16_t u16x4  __attribute__((ext_vector_type(4)));

#define DEV __device__ __forceinline__
#define AS1 __attribute__((address_space(1)))
#define AS3 __attribute__((address_space(3)))

#define SM_SCALE 0.18033688011112042f   // log2(e)/sqrt(Dh) = log2(e)/8, folded into Wq

DEV uint32_t pk_bf16(float lo, float hi) {
    uint32_t r;
    asm("v_cvt_pk_bf16_f32 %0, %1, %2" : "=v"(r) : "v"(lo), "v"(hi));
    return r;
}

// async global->LDS, 16B per lane; LDS dest = wave-uniform base + lane*16
DEV void gload_lds16(const void* g, void* l) {
    __builtin_amdgcn_global_load_lds((AS1 const uint32_t*)g, (AS3 uint32_t*)l, 16, 0, 0);
}

// v_permlane32_swap_b32 a, b: a.hi(rows 2-3) <-> b.lo(rows 0-1).
// Direction HW-verified: round-4 (swapped operands) failed, round-6 (this order) passed.
DEV void plane32_swap(uint32_t& a, uint32_t& b) {
    asm("v_permlane32_swap_b32 %0, %1" : "+v"(a), "+v"(b));
}

// ---------------------------------------------------------------------------
// cast fp32 -> bf16: y in [0,3] -> weights (1M elems), y in [4,6] -> activations (4M)
// Wq (y==0) is pre-scaled by SM_SCALE so attention scores land in log2 domain.
// ---------------------------------------------------------------------------
__global__ __launch_bounds__(256) void cast_all(
    const float* __restrict__ w0, const float* __restrict__ w1,
    const float* __restrict__ w2, const float* __restrict__ w3,
    const float* __restrict__ aq, const float* __restrict__ ak, const float* __restrict__ av,
    uint16_t* __restrict__ ws)
{
    const int y = blockIdx.y;
    const float* s;
    uint16_t* d;
    if (y < 4) {
        if (blockIdx.x >= 512) return;
        s = (y == 0) ? w0 : (y == 1) ? w1 : (y == 2) ? w2 : w3;
        d = ws + ((size_t)y << 20);
    } else {
        s = (y == 4) ? aq : (y == 5) ? ak : av;
        d = ws + (size_t)(1 << 22) + ((size_t)(y - 4) << 22);
    }
    const float m = (y == 0) ? SM_SCALE : 1.0f;
    const size_t i = ((size_t)blockIdx.x * 256 + threadIdx.x) * 8;
    float4 a = *reinterpret_cast<const float4*>(s + i);
    float4 b = *reinterpret_cast<const float4*>(s + i + 4);
    u32x4 w;
    w[0] = pk_bf16(a.x * m, a.y * m); w[1] = pk_bf16(a.z * m, a.w * m);
    w[2] = pk_bf16(b.x * m, b.y * m); w[3] = pk_bf16(b.z * m, b.w * m);
    *reinterpret_cast<u32x4*>(d + i) = w;
}

// ---------------------------------------------------------------------------
// QKV GEMM, round-12: 64x128 tile (BM=64 for 6 blocks/CU), BK=64 plane-split
// LDS (verified bank layout), global_load_lds staging. 4 waves as 2x2,
// acc[2][4] per wave. Weights re-read 64x but L2-resident (2 MB bf16).
// blockIdx.z: 0->Q (bias scaled), 1->K, 2->V (stored transposed per head)
// ---------------------------------------------------------------------------
__global__ __launch_bounds__(256) void gemm_qkv(
    const uint16_t* __restrict__ Qc, const uint16_t* __restrict__ Kc, const uint16_t* __restrict__ Vc,
    const uint16_t* __restrict__ wqc, const uint16_t* __restrict__ wkc, const uint16_t* __restrict__ wvc,
    const float* __restrict__ bq, const float* __restrict__ bk, const float* __restrict__ bv,
    uint16_t* __restrict__ Qb, uint16_t* __restrict__ Kb, uint16_t* __restrict__ Vt)
{
    constexpr int Kd = 1024, N = 1024;
    __shared__ uint16_t Al[2][64 * 32];    // plane p = K-cols [32p, 32p+32)
    __shared__ uint16_t Bl[2][128 * 32];

    const int z = blockIdx.z;
    const uint16_t* A = (z == 0) ? Qc : (z == 1) ? Kc : Vc;
    const uint16_t* W = (z == 0) ? wqc : (z == 1) ? wkc : wvc;
    const float* bias = (z == 0) ? bq : (z == 1) ? bk : bv;
    const float bs = (z == 0) ? SM_SCALE : 1.0f;

    const int brow = blockIdx.x * 64;
    const int bcol = blockIdx.y * 128;
    const int t = threadIdx.x, lane = t & 63, wid = t >> 6;
    const int wr = wid >> 1, wc = wid & 1;

    // staging map: row = wid*16 + (lane>>2) in [0,64), col = (lane&3)*8
    const int srow = wid * 16 + (lane >> 2);
    const int scol = (lane & 3) * 8;
    const uint16_t* aA = A + (size_t)(brow + srow) * Kd + scol;
    const uint16_t* aW = W + (size_t)(bcol + srow) * Kd + scol;
    uint16_t* lA = &Al[0][srow * 32 + scol];
    uint16_t* lB = &Bl[0][srow * 32 + scol];

    f32x4 acc[2][4];
#pragma unroll
    for (int i = 0; i < 2; ++i)
#pragma unroll
        for (int j = 0; j < 4; ++j)
#pragma unroll
            for (int e = 0; e < 4; ++e) acc[i][j][e] = 0.f;

    const int frow = lane & 15;
    const int koff = (lane >> 4) * 8;

    for (int k0 = 0; k0 < Kd; k0 += 64) {
#pragma unroll
        for (int p = 0; p < 2; ++p) {
            gload_lds16(aA + k0 + p * 32, lA + p * 2048);
            gload_lds16(aW + k0 + p * 32, lB + p * 4096);
            gload_lds16(aW + k0 + p * 32 + (size_t)64 * Kd, lB + p * 4096 + 2048);
        }
        __syncthreads();

#pragma unroll
        for (int p = 0; p < 2; ++p) {
            bf16x8 af[2], bfr[4];
#pragma unroll
            for (int fr = 0; fr < 2; ++fr)
                af[fr] = *reinterpret_cast<const bf16x8*>(&Al[p][(wr * 32 + fr * 16 + frow) * 32 + koff]);
#pragma unroll
            for (int fc = 0; fc < 4; ++fc)
                bfr[fc] = *reinterpret_cast<const bf16x8*>(&Bl[p][(wc * 64 + fc * 16 + frow) * 32 + koff]);
#pragma unroll
            for (int fr = 0; fr < 2; ++fr)
#pragma unroll
                for (int fc = 0; fc < 4; ++fc)
                    acc[fr][fc] = __builtin_amdgcn_mfma_f32_16x16x32_bf16(af[fr], bfr[fc], acc[fr][fc], 0, 0, 0);
        }
        __syncthreads();
    }

    const int m0 = brow + wr * 32;
    const int n0 = bcol + wc * 64;
    if (z < 2) {
        uint16_t* Cb = (z == 0) ? Qb : Kb;
#pragma unroll
        for (int fc = 0; fc < 4; ++fc) {
            const int col = n0 + fc * 16 + frow;
            const float bia = bias[col] * bs;
#pragma unroll
            for (int fr = 0; fr < 2; ++fr) {
                const int mrow = m0 + fr * 16 + (lane >> 4) * 4;
                f32x4 a = acc[fr][fc];
                uint32_t w01 = pk_bf16(a[0] + bia, a[1] + bia);
                uint32_t w23 = pk_bf16(a[2] + bia, a[3] + bia);
                Cb[(size_t)(mrow + 0) * N + col] = (uint16_t)(w01 & 0xffff);
                Cb[(size_t)(mrow + 1) * N + col] = (uint16_t)(w01 >> 16);
                Cb[(size_t)(mrow + 2) * N + col] = (uint16_t)(w23 & 0xffff);
                Cb[(size_t)(mrow + 3) * N + col] = (uint16_t)(w23 >> 16);
            }
        }
    } else {
        // V: store transposed per head -> Vt[((b*16+h)*64+d)*2048 + s]
#pragma unroll
        for (int fc = 0; fc < 4; ++fc) {
            const int col = n0 + fc * 16 + frow;
            const int hh = col >> 6, dd = col & 63;
            const float bia = bias[col];
#pragma unroll
            for (int fr = 0; fr < 2; ++fr) {
                const int mrow = m0 + fr * 16 + (lane >> 4) * 4;
                const int bb = mrow >> 11, ss = mrow & 2047;
                f32x4 a = acc[fr][fc];
                uint32_t w01 = pk_bf16(a[0] + bia, a[1] + bia);
                uint32_t w23 = pk_bf16(a[2] + bia, a[3] + bia);
                u16x4 pv;
                pv[0] = (uint16_t)(w01 & 0xffff); pv[1] = (uint16_t)(w01 >> 16);
                pv[2] = (uint16_t)(w23 & 0xffff); pv[3] = (uint16_t)(w23 >> 16);
                *reinterpret_cast<u16x4*>(&Vt[(size_t)((bb * 16 + hh) * 64 + dd) * 2048 + ss]) = pv;
            }
        }
    }
}

// ---------------------------------------------------------------------------
// Flash attention (round-8/9 verified, verbatim): in-block KV-split,
// LDS-staged K/V, 2 barriers/tile, 4 blocks/CU.
// ---------------------------------------------------------------------------
__global__ __launch_bounds__(256, 4) void attn_kernel(
    const uint16_t* __restrict__ Qb, const uint16_t* __restrict__ Kb,
    const uint16_t* __restrict__ Vt, uint16_t* __restrict__ At)
{
    constexpr int S = 2048, E = 1024;
    __shared__ uint16_t Kl[2][64 * 72];
    __shared__ uint16_t Vl[2][64 * 72];

    const int bh = blockIdx.y;
    const int b = bh >> 4, h = bh & 15;
    const int t = threadIdx.x;
    const int lane = t & 63, wid = t >> 6;
    const int lo = lane & 31, hi = lane >> 5;
    const int half = wid >> 1;
    const int q0 = blockIdx.x * 64 + (wid & 1) * 32;

    bf16x8 qf[4];
    {
        const uint16_t* qrow = Qb + (size_t)(b * S + q0 + lo) * E + h * 64;
#pragma unroll
        for (int kk = 0; kk < 4; ++kk)
            qf[kk] = *reinterpret_cast<const bf16x8*>(qrow + kk * 16 + hi * 8);
    }

    f32x16 oacc[2];
#pragma unroll
    for (int i = 0; i < 16; ++i) { oacc[0][i] = 0.f; oacc[1][i] = 0.f; }
    float mrun = -1e30f, lsum = 0.f;

    const uint16_t* Kbase = Kb + (size_t)(b * S) * E + h * 64;
    const uint16_t* Vbase = Vt + (size_t)(bh * 64) * S;

    const int r = t >> 2, seg = t & 3;
    const int lds_off = r * 72 + seg * 16;

#pragma unroll 1
    for (int i = 0; i < 16; ++i) {
        {
            const uint16_t* ksa = Kbase + (size_t)(i * 64 + r) * E + seg * 16;
            const uint16_t* vsa = Vbase + (size_t)r * S + i * 64 + seg * 16;
            const uint16_t* ksb = ksa + (size_t)1024 * E;
            const uint16_t* vsb = vsa + 1024;
            u32x4 k0a = *reinterpret_cast<const u32x4*>(ksa);
            u32x4 k1a = *reinterpret_cast<const u32x4*>(ksa + 8);
            u32x4 v0a = *reinterpret_cast<const u32x4*>(vsa);
            u32x4 v1a = *reinterpret_cast<const u32x4*>(vsa + 8);
            u32x4 k0b = *reinterpret_cast<const u32x4*>(ksb);
            u32x4 k1b = *reinterpret_cast<const u32x4*>(ksb + 8);
            u32x4 v0b = *reinterpret_cast<const u32x4*>(vsb);
            u32x4 v1b = *reinterpret_cast<const u32x4*>(vsb + 8);
            *reinterpret_cast<u32x4*>(&Kl[0][lds_off])     = k0a;
            *reinterpret_cast<u32x4*>(&Kl[0][lds_off + 8]) = k1a;
            *reinterpret_cast<u32x4*>(&Vl[0][lds_off])     = v0a;
            *reinterpret_cast<u32x4*>(&Vl[0][lds_off + 8]) = v1a;
            *reinterpret_cast<u32x4*>(&Kl[1][lds_off])     = k0b;
            *reinterpret_cast<u32x4*>(&Kl[1][lds_off + 8]) = k1b;
            *reinterpret_cast<u32x4*>(&Vl[1][lds_off])     = v0b;
            *reinterpret_cast<u32x4*>(&Vl[1][lds_off + 8]) = v1b;
        }
        __syncthreads();

        f32x16 sacc[2];
#pragma unroll
        for (int j = 0; j < 16; ++j) { sacc[0][j] = 0.f; sacc[1][j] = 0.f; }
        __builtin_amdgcn_s_setprio(1);
#pragma unroll
        for (int kk = 0; kk < 4; ++kk) {
            bf16x8 ka0 = *reinterpret_cast<const bf16x8*>(&Kl[half][lo * 72 + kk * 16 + hi * 8]);
            bf16x8 ka1 = *reinterpret_cast<const bf16x8*>(&Kl[half][(32 + lo) * 72 + kk * 16 + hi * 8]);
            sacc[0] = __builtin_amdgcn_mfma_f32_32x32x16_bf16(ka0, qf[kk], sacc[0], 0, 0, 0);
            sacc[1] = __builtin_amdgcn_mfma_f32_32x32x16_bf16(ka1, qf[kk], sacc[1], 0, 0, 0);
        }
        __builtin_amdgcn_s_setprio(0);

        float tm[16];
#pragma unroll
        for (int j = 0; j < 16; ++j) tm[j] = fmaxf(sacc[0][j], sacc[1][j]);
#pragma unroll
        for (int s = 8; s > 0; s >>= 1)
#pragma unroll
            for (int j = 0; j < 8; ++j)
                if (j < s) tm[j] = fmaxf(tm[j], tm[j + s]);
        float pmax = tm[0];
        pmax = fmaxf(pmax, __shfl_xor(pmax, 32, 64));

        if (!__all(pmax - mrun <= 3.0f)) {
            float mnew = fmaxf(mrun, pmax);
            float corr = __builtin_amdgcn_exp2f(mrun - mnew);
            lsum *= corr;
#pragma unroll
            for (int j = 0; j < 16; ++j) { oacc[0][j] *= corr; oacc[1][j] *= corr; }
            mrun = mnew;
        }

        uint32_t w[16];
        float ps0 = 0.f, ps1 = 0.f, ps2 = 0.f, ps3 = 0.f;
#pragma unroll
        for (int kf = 0; kf < 2; ++kf)
#pragma unroll
            for (int j = 0; j < 8; ++j) {
                float pa = __builtin_amdgcn_exp2f(sacc[kf][2 * j]     - mrun);
                float pb = __builtin_amdgcn_exp2f(sacc[kf][2 * j + 1] - mrun);
                if (j & 1) { ps0 += pa; ps1 += pb; } else { ps2 += pa; ps3 += pb; }
                w[kf * 8 + j] = pk_bf16(pa, pb);
            }
        lsum += (ps0 + ps1) + (ps2 + ps3);

        __builtin_amdgcn_s_setprio(1);
#pragma unroll
        for (int ks = 0; ks < 4; ++ks) {
            const int base = (ks >> 1) * 8 + (ks & 1) * 4;
            uint32_t p0 = w[base + 0], p2 = w[base + 2];
            uint32_t p1 = w[base + 1], p3 = w[base + 3];
            plane32_swap(p0, p2);
            plane32_swap(p1, p3);
            u32x4 pw; pw[0] = p0; pw[1] = p1; pw[2] = p2; pw[3] = p3;
            bf16x8 pf = __builtin_bit_cast(bf16x8, pw);
#pragma unroll
            for (int df = 0; df < 2; ++df) {
                bf16x8 vf = *reinterpret_cast<const bf16x8*>(&Vl[half][(df * 32 + lo) * 72 + ks * 16 + hi * 8]);
                oacc[df] = __builtin_amdgcn_mfma_f32_32x32x16_bf16(vf, pf, oacc[df], 0, 0, 0);
            }
        }
        __builtin_amdgcn_s_setprio(0);
        __syncthreads();
    }

    lsum += __shfl_xor(lsum, 32, 64);

    float* ob  = reinterpret_cast<float*>(&Kl[0][0]);
    float* mlb = reinterpret_cast<float*>(&Vl[0][0]);
    const int w2 = wid & 1;
    if (half == 1) {
        float* dst = ob + (w2 * 64 + lane) * 36;
#pragma unroll
        for (int df = 0; df < 2; ++df)
#pragma unroll
            for (int j = 0; j < 16; ++j) dst[df * 16 + j] = oacc[df][j];
        mlb[(w2 * 64 + lane) * 2]     = mrun;
        mlb[(w2 * 64 + lane) * 2 + 1] = lsum;
    }
    __syncthreads();
    if (half == 0) {
        const float* src = ob + (w2 * 64 + lane) * 36;
        const float m1 = mlb[(w2 * 64 + lane) * 2];
        const float l1 = mlb[(w2 * 64 + lane) * 2 + 1];
        const float m  = fmaxf(mrun, m1);
        const float c0 = __builtin_amdgcn_exp2f(mrun - m);
        const float c1 = __builtin_amdgcn_exp2f(m1 - m);
        const float inv = 1.0f / (c0 * lsum + c1 * l1);
        uint16_t* orow = At + (size_t)(b * S + q0 + lo) * E + h * 64;
#pragma unroll
        for (int df = 0; df < 2; ++df)
#pragma unroll
            for (int g = 0; g < 4; ++g) {
                float e0 = (c0 * oacc[df][4 * g + 0] + c1 * src[df * 16 + 4 * g + 0]) * inv;
                float e1 = (c0 * oacc[df][4 * g + 1] + c1 * src[df * 16 + 4 * g + 1]) * inv;
                float e2 = (c0 * oacc[df][4 * g + 2] + c1 * src[df * 16 + 4 * g + 2]) * inv;
                float e3 = (c0 * oacc[df][4 * g + 3] + c1 * src[df * 16 + 4 * g + 3]) * inv;
                uint32_t w01 = pk_bf16(e0, e1);
                uint32_t w23 = pk_bf16(e2, e3);
                u32x2 o2; o2[0] = w01; o2[1] = w23;
                *reinterpret_cast<u32x2*>(orow + df * 32 + 8 * g + 4 * hi) = o2;
            }
    }
}

// ---------------------------------------------------------------------------
// Output projection, round-12: same 64x128 / BK=64 structure as gemm_qkv.
// ---------------------------------------------------------------------------
__global__ __launch_bounds__(256) void gemm_out(
    const uint16_t* __restrict__ Atn, const uint16_t* __restrict__ woc,
    const float* __restrict__ bo, float* __restrict__ out)
{
    constexpr int Kd = 1024, N = 1024;
    __shared__ uint16_t Al[2][64 * 32];
    __shared__ uint16_t Bl[2][128 * 32];

    const int brow = blockIdx.x * 64;
    const int bcol = blockIdx.y * 128;
    const int t = threadIdx.x, lane = t & 63, wid = t >> 6;
    const int wr = wid >> 1, wc = wid & 1;

    const int srow = wid * 16 + (lane >> 2);
    const int scol = (lane & 3) * 8;
    const uint16_t* aA = Atn + (size_t)(brow + srow) * Kd + scol;
    const uint16_t* aW = woc + (size_t)(bcol + srow) * Kd + scol;
    uint16_t* lA = &Al[0][srow * 32 + scol];
    uint16_t* lB = &Bl[0][srow * 32 + scol];

    f32x4 acc[2][4];
#pragma unroll
    for (int i = 0; i < 2; ++i)
#pragma unroll
        for (int j = 0; j < 4; ++j)
#pragma unroll
            for (int e = 0; e < 4; ++e) acc[i][j][e] = 0.f;

    const int frow = lane & 15;
    const int koff = (lane >> 4) * 8;

    for (int k0 = 0; k0 < Kd; k0 += 64) {
#pragma unroll
        for (int p = 0; p < 2; ++p) {
            gload_lds16(aA + k0 + p * 32, lA + p * 2048);
            gload_lds16(aW + k0 + p * 32, lB + p * 4096);
            gload_lds16(aW + k0 + p * 32 + (size_t)64 * Kd, lB + p * 4096 + 2048);
        }
        __syncthreads();

#pragma unroll
        for (int p = 0; p < 2; ++p) {
            bf16x8 af[2], bfr[4];
#pragma unroll
            for (int fr = 0; fr < 2; ++fr)
                af[fr] = *reinterpret_cast<const bf16x8*>(&Al[p][(wr * 32 + fr * 16 + frow) * 32 + koff]);
#pragma unroll
            for (int fc = 0; fc < 4; ++fc)
                bfr[fc] = *reinterpret_cast<const bf16x8*>(&Bl[p][(wc * 64 + fc * 16 + frow) * 32 + koff]);
#pragma unroll
            for (int fr = 0; fr < 2; ++fr)
#pragma unroll
                for (int fc = 0; fc < 4; ++fc)
                    acc[fr][fc] = __builtin_amdgcn_mfma_f32_16x16x32_bf16(af[fr], bfr[fc], acc[fr][fc], 0, 0, 0);
        }
        __syncthreads();
    }

    const int m0 = brow + wr * 32;
    const int n0 = bcol + wc * 64;
#pragma unroll
    for (int fc = 0; fc < 4; ++fc) {
        const int col = n0 + fc * 16 + frow;
        const float bia = bo[col];
#pragma unroll
        for (int fr = 0; fr < 2; ++fr) {
            const int mrow = m0 + fr * 16 + (lane >> 4) * 4;
#pragma unroll
            for (int j = 0; j < 4; ++j)
                out[(size_t)(mrow + j) * N + col] = acc[fr][fc][j] + bia;
        }
    }
}

// ---------------------------------------------------------------------------
extern "C" void kernel_launch(void* const* d_in, const int* in_sizes, int n_in,
                              void* d_out, int out_size, void* d_ws, size_t ws_size,
                              hipStream_t stream)
{
    const float* key   = (const float*)d_in[0];
    const float* query = (const float*)d_in[1];
    const float* value = (const float*)d_in[2];
    const float* Wq = (const float*)d_in[3];
    const float* bq = (const float*)d_in[4];
    const float* Wk = (const float*)d_in[5];
    const float* bk = (const float*)d_in[6];
    const float* Wv = (const float*)d_in[7];
    const float* bv = (const float*)d_in[8];
    const float* Wo = (const float*)d_in[9];
    const float* bo = (const float*)d_in[10];

    uint16_t* ws = (uint16_t*)d_ws;
    uint16_t* wqc = ws;                                 // 4 x 1M weights
    uint16_t* wkc = ws + ((size_t)1 << 20);
    uint16_t* wvc = ws + ((size_t)2 << 20);
    uint16_t* woc = ws + ((size_t)3 << 20);
    uint16_t* Qc  = ws + ((size_t)1 << 22);             // 3 x 4M bf16 activations
    uint16_t* Kc  = ws + ((size_t)2 << 22);
    uint16_t* Vc  = ws + ((size_t)3 << 22);
    uint16_t* Qb  = ws + ((size_t)4 << 22);             // projected Q/K, V^T
    uint16_t* Kb  = ws + ((size_t)5 << 22);
    uint16_t* Vt  = ws + ((size_t)6 << 22);
    uint16_t* At  = Qc;                                 // alias: Qc dead after gemm_qkv
    float* out = (float*)d_out;

    cast_all<<<dim3(2048, 7), 256, 0, stream>>>(Wq, Wk, Wv, Wo, query, key, value, ws);
    gemm_qkv<<<dim3(64, 8, 3), 256, 0, stream>>>(Qc, Kc, Vc, wqc, wkc, wvc,
                                                 bq, bk, bv, Qb, Kb, Vt);
    attn_kernel<<<dim3(32, 32), 256, 0, stream>>>(Qb, Kb, Vt, At);
    gemm_out<<<dim3(64, 8), 256, 0, stream>>>(At, woc, bo, out);
}